// Round 1
// baseline (19798.395 us; speedup 1.0000x reference)
//
#include <hip/hip_runtime.h>
#include <math.h>

#define TT 64
#define BB 2048
#define DD 512
#define HH 512

__device__ __forceinline__ float wred(float v) {
#pragma unroll
    for (int m = 32; m > 0; m >>= 1) v += __shfl_xor(v, m);
    return v;
}

// MODE 0: y = LN(x; g,b)                     (xn)
// MODE 1: y = LN(x; g,b) * exp(-clip(dt))    (hn, needs ts,t)
// MODE 2: y = LN(x; g,b), also write y2      (cell LN -> h and states[t])
template<int MODE>
__global__ __launch_bounds__(256)
void ln_kernel(const float* __restrict__ x, const float* __restrict__ g,
               const float* __restrict__ b, float* __restrict__ y,
               float* __restrict__ y2, const float* __restrict__ ts, int t)
{
    const int wave = threadIdx.x >> 6;
    const int lane = threadIdx.x & 63;
    const int row  = blockIdx.x * 4 + wave;   // rows = BB
    const float* xr = x + (size_t)row * 512;
    const int c0 = lane * 8;

    float4 v0 = *(const float4*)(xr + c0);
    float4 v1 = *(const float4*)(xr + c0 + 4);

    float s  = v0.x + v0.y + v0.z + v0.w + v1.x + v1.y + v1.z + v1.w;
    float ss = v0.x*v0.x + v0.y*v0.y + v0.z*v0.z + v0.w*v0.w
             + v1.x*v1.x + v1.y*v1.y + v1.z*v1.z + v1.w*v1.w;
    s  = wred(s);
    ss = wred(ss);
    const float mean = s * (1.0f / 512.0f);
    const float var  = ss * (1.0f / 512.0f) - mean * mean;
    const float rs   = rsqrtf(var + 1e-5f);

    float scale = 1.0f;
    if (MODE == 1) {
        float dt = ts[row * TT + t] - ts[row * TT + t - 1];
        dt = fminf(fmaxf(dt, 0.0f), 10.0f);
        scale = expf(-dt);
    }

    float4 g0 = *(const float4*)(g + c0);
    float4 g1 = *(const float4*)(g + c0 + 4);
    float4 b0 = *(const float4*)(b + c0);
    float4 b1 = *(const float4*)(b + c0 + 4);

    float4 o0, o1;
    o0.x = ((v0.x - mean) * rs * g0.x + b0.x) * scale;
    o0.y = ((v0.y - mean) * rs * g0.y + b0.y) * scale;
    o0.z = ((v0.z - mean) * rs * g0.z + b0.z) * scale;
    o0.w = ((v0.w - mean) * rs * g0.w + b0.w) * scale;
    o1.x = ((v1.x - mean) * rs * g1.x + b1.x) * scale;
    o1.y = ((v1.y - mean) * rs * g1.y + b1.y) * scale;
    o1.z = ((v1.z - mean) * rs * g1.z + b1.z) * scale;
    o1.w = ((v1.w - mean) * rs * g1.w + b1.w) * scale;

    float* yr = y + (size_t)row * 512;
    *(float4*)(yr + c0)     = o0;
    *(float4*)(yr + c0 + 4) = o1;
    if (MODE == 2) {
        float* y2r = y2 + (size_t)row * 512;
        *(float4*)(y2r + c0)     = o0;
        *(float4*)(y2r + c0 + 4) = o1;
    }
}

// C[M=2048, N=512] = A[M, K=1024] @ W[N, K]^T, A = [xn | hn] (EPI 0) or [xn | r*hn] (EPI 1)
// EPI 0: out = sigmoid(C + bias)
// EPI 1: out = (1-z)*hn + z*tanh(C + bias)
template<int EPI>
__global__ __launch_bounds__(256)
void gemm_step(const float* __restrict__ xn, const float* __restrict__ hn,
               const float* __restrict__ rb, const float* __restrict__ zb,
               const float* __restrict__ W, const float* __restrict__ bias,
               float* __restrict__ out)
{
    __shared__ float As[32][68];
    __shared__ float Bs[32][68];
    const int tid = threadIdx.x;
    const int m0 = blockIdx.y * 64;
    const int n0 = blockIdx.x * 64;
    const int lr = tid >> 3;     // 0..31
    const int kq = tid & 7;      // 0..7
    const int tm = tid >> 4;     // 0..15
    const int tn = tid & 15;     // 0..15

    float acc[4][4] = {};

    for (int kt = 0; kt < 1024; kt += 32) {
        const int col = kt + kq * 4;
        const bool hpart = (col >= 512);
        const int cc = hpart ? (col - 512) : col;
#pragma unroll
        for (int rr = 0; rr < 2; ++rr) {
            const int rl = lr + rr * 32;
            const int row = m0 + rl;
            float4 v;
            if (!hpart) {
                v = *(const float4*)(xn + (size_t)row * 512 + cc);
            } else {
                v = *(const float4*)(hn + (size_t)row * 512 + cc);
                if (EPI == 1) {
                    float4 rv = *(const float4*)(rb + (size_t)row * 512 + cc);
                    v.x *= rv.x; v.y *= rv.y; v.z *= rv.z; v.w *= rv.w;
                }
            }
            As[kq * 4 + 0][rl] = v.x;
            As[kq * 4 + 1][rl] = v.y;
            As[kq * 4 + 2][rl] = v.z;
            As[kq * 4 + 3][rl] = v.w;
        }
#pragma unroll
        for (int rr = 0; rr < 2; ++rr) {
            const int j = lr + rr * 32;
            float4 w = *(const float4*)(W + (size_t)(n0 + j) * 1024 + col);
            Bs[kq * 4 + 0][j] = w.x;
            Bs[kq * 4 + 1][j] = w.y;
            Bs[kq * 4 + 2][j] = w.z;
            Bs[kq * 4 + 3][j] = w.w;
        }
        __syncthreads();
#pragma unroll
        for (int kk = 0; kk < 32; ++kk) {
            float4 av = *(const float4*)&As[kk][tm * 4];
            float4 bv = *(const float4*)&Bs[kk][tn * 4];
            const float aa[4] = {av.x, av.y, av.z, av.w};
            const float bb2[4] = {bv.x, bv.y, bv.z, bv.w};
#pragma unroll
            for (int i = 0; i < 4; ++i)
#pragma unroll
                for (int j = 0; j < 4; ++j)
                    acc[i][j] += aa[i] * bb2[j];
        }
        __syncthreads();
    }

#pragma unroll
    for (int i = 0; i < 4; ++i) {
        const int row = m0 + tm * 4 + i;
        const int c  = n0 + tn * 4;
        float4 o;
        float vals[4];
#pragma unroll
        for (int j = 0; j < 4; ++j) {
            float v = acc[i][j] + bias[c + j];
            if (EPI == 0) {
                vals[j] = 1.0f / (1.0f + expf(-v));
            } else {
                float ht = tanhf(v);
                float z  = zb[(size_t)row * 512 + c + j];
                float hp = hn[(size_t)row * 512 + c + j];
                vals[j] = (1.0f - z) * hp + z * ht;
            }
        }
        o.x = vals[0]; o.y = vals[1]; o.z = vals[2]; o.w = vals[3];
        *(float4*)(out + (size_t)row * 512 + c) = o;
    }
}

// out[r,:] = LN( S[r,:] @ Wo^T + bo + seq[r,:] ; gf, bf )   in-place safe (S == out)
__global__ __launch_bounds__(256)
void proj_ln_kernel(const float* __restrict__ S, const float* __restrict__ Wo,
                    const float* __restrict__ bo, const float* __restrict__ seq,
                    const float* __restrict__ gf, const float* __restrict__ bf,
                    float* __restrict__ out)
{
    __shared__ float Ssh[16][512];
    const int tid = threadIdx.x;
    const long row0 = (long)blockIdx.x * 16;

#pragma unroll
    for (int i = 0; i < 8; ++i) {
        const int idx = tid + i * 256;      // float4 index
        const int r = idx >> 7;
        const int c = (idx & 127) * 4;
        *(float4*)&Ssh[r][c] = *(const float4*)(S + (row0 + r) * 512 + c);
    }
    __syncthreads();

    const int wv = tid >> 6;    // 0..3 -> rows wv*4..wv*4+3
    const int lane = tid & 63;  // cols lane*8..lane*8+7

    float acc[4][8] = {};
    for (int k = 0; k < 512; k += 4) {
        float4 s0 = *(const float4*)&Ssh[wv * 4 + 0][k];
        float4 s1 = *(const float4*)&Ssh[wv * 4 + 1][k];
        float4 s2 = *(const float4*)&Ssh[wv * 4 + 2][k];
        float4 s3 = *(const float4*)&Ssh[wv * 4 + 3][k];
#pragma unroll
        for (int j = 0; j < 8; ++j) {
            float4 w = *(const float4*)(Wo + (size_t)(lane * 8 + j) * 512 + k);
            acc[0][j] += s0.x * w.x + s0.y * w.y + s0.z * w.z + s0.w * w.w;
            acc[1][j] += s1.x * w.x + s1.y * w.y + s1.z * w.z + s1.w * w.w;
            acc[2][j] += s2.x * w.x + s2.y * w.y + s2.z * w.z + s2.w * w.w;
            acc[3][j] += s3.x * w.x + s3.y * w.y + s3.z * w.z + s3.w * w.w;
        }
    }

    const int c0 = lane * 8;
    float4 bo0 = *(const float4*)(bo + c0);
    float4 bo1 = *(const float4*)(bo + c0 + 4);
    float4 gf0 = *(const float4*)(gf + c0);
    float4 gf1 = *(const float4*)(gf + c0 + 4);
    float4 bf0 = *(const float4*)(bf + c0);
    float4 bf1 = *(const float4*)(bf + c0 + 4);
    const float boa[8] = {bo0.x, bo0.y, bo0.z, bo0.w, bo1.x, bo1.y, bo1.z, bo1.w};
    const float gfa[8] = {gf0.x, gf0.y, gf0.z, gf0.w, gf1.x, gf1.y, gf1.z, gf1.w};
    const float bfa[8] = {bf0.x, bf0.y, bf0.z, bf0.w, bf1.x, bf1.y, bf1.z, bf1.w};

#pragma unroll
    for (int i = 0; i < 4; ++i) {
        const long row = row0 + wv * 4 + i;
        float4 q0 = *(const float4*)(seq + row * 512 + c0);
        float4 q1 = *(const float4*)(seq + row * 512 + c0 + 4);
        const float sq[8] = {q0.x, q0.y, q0.z, q0.w, q1.x, q1.y, q1.z, q1.w};
        float s = 0.0f, ss = 0.0f;
#pragma unroll
        for (int j = 0; j < 8; ++j) {
            float v = acc[i][j] + boa[j] + sq[j];
            acc[i][j] = v;
            s += v; ss += v * v;
        }
        s = wred(s); ss = wred(ss);
        const float mean = s * (1.0f / 512.0f);
        const float var  = ss * (1.0f / 512.0f) - mean * mean;
        const float rs   = rsqrtf(var + 1e-5f);
        float o[8];
#pragma unroll
        for (int j = 0; j < 8; ++j)
            o[j] = (acc[i][j] - mean) * rs * gfa[j] + bfa[j];
        float4 w0, w1;
        w0.x = o[0]; w0.y = o[1]; w0.z = o[2]; w0.w = o[3];
        w1.x = o[4]; w1.y = o[5]; w1.z = o[6]; w1.w = o[7];
        *(float4*)(out + row * 512 + c0)     = w0;
        *(float4*)(out + row * 512 + c0 + 4) = w1;
    }
}

extern "C" void kernel_launch(void* const* d_in, const int* in_sizes, int n_in,
                              void* d_out, int out_size, void* d_ws, size_t ws_size,
                              hipStream_t stream) {
    const float* seq = (const float*)d_in[0];
    const float* ts  = (const float*)d_in[1];
    const float* Wr  = (const float*)d_in[2];
    const float* br  = (const float*)d_in[3];
    const float* Wz  = (const float*)d_in[4];
    const float* bz  = (const float*)d_in[5];
    const float* Wc  = (const float*)d_in[6];
    const float* bc  = (const float*)d_in[7];
    const float* Wo  = (const float*)d_in[8];
    const float* bo  = (const float*)d_in[9];
    const float* gx  = (const float*)d_in[10];
    const float* bx  = (const float*)d_in[11];
    const float* gh  = (const float*)d_in[12];
    const float* bh  = (const float*)d_in[13];
    const float* gc  = (const float*)d_in[14];
    const float* bcl = (const float*)d_in[15];
    const float* gf  = (const float*)d_in[16];
    const float* bf  = (const float*)d_in[17];
    float* out = (float*)d_out;
    float* ws  = (float*)d_ws;

    const size_t NBH = (size_t)BB * HH;   // 1M floats
    float* xn   = ws;
    float* hn   = ws + 1 * NBH;
    float* rb   = ws + 2 * NBH;
    float* zb   = ws + 3 * NBH;
    float* hraw = ws + 4 * NBH;
    float* h    = ws + 5 * NBH;

    hipMemsetAsync(hn, 0, NBH * sizeof(float), stream);

    dim3 gemmGrid(8, 32);   // (N/64, M/64)
    for (int t = 0; t < TT; ++t) {
        ln_kernel<0><<<512, 256, 0, stream>>>(seq + (size_t)t * BB * DD, gx, bx, xn, nullptr, nullptr, 0);
        if (t > 0)
            ln_kernel<1><<<512, 256, 0, stream>>>(h, gh, bh, hn, nullptr, ts, t);
        gemm_step<0><<<gemmGrid, 256, 0, stream>>>(xn, hn, nullptr, nullptr, Wr, br, rb);
        gemm_step<0><<<gemmGrid, 256, 0, stream>>>(xn, hn, nullptr, nullptr, Wz, bz, zb);
        gemm_step<1><<<gemmGrid, 256, 0, stream>>>(xn, hn, rb, zb, Wc, bc, hraw);
        ln_kernel<2><<<512, 256, 0, stream>>>(hraw, gc, bcl, h, out + (size_t)t * BB * HH, nullptr, 0);
    }
    proj_ln_kernel<<<8192, 256, 0, stream>>>(out, Wo, bo, seq, gf, bf, out);
}

// Round 2
// 11197.518 us; speedup vs baseline: 1.7681x; 1.7681x over previous
//
#include <hip/hip_runtime.h>
#include <math.h>

#define TT 64
#define BB 2048

using f32x4  = __attribute__((ext_vector_type(4))) float;
using short8 = __attribute__((ext_vector_type(8))) short;

__device__ __forceinline__ unsigned short f2bf(float f) {
    unsigned u = __float_as_uint(f);
    u += 0x7FFF + ((u >> 16) & 1);
    return (unsigned short)(u >> 16);
}
__device__ __forceinline__ float sigmoidf_(float v) { return 1.0f / (1.0f + expf(-v)); }
__device__ __forceinline__ float tanhf_(float v)    { return 1.0f - 2.0f / (expf(2.0f * v) + 1.0f); }

// ---------------- weight f32 -> bf16 convert ----------------
__global__ __launch_bounds__(256)
void cvt_kernel(const float* __restrict__ src, unsigned short* __restrict__ dst, int n) {
    int i = blockIdx.x * 256 + threadIdx.x;
    if (i < n) dst[i] = f2bf(src[i]);
}

// ---------------- LN(x; g,b) -> bf16, one wave per row ----------------
__global__ __launch_bounds__(256)
void ln_x_kernel(const float* __restrict__ x, const float* __restrict__ g,
                 const float* __restrict__ b, unsigned short* __restrict__ y)
{
    const int wave = threadIdx.x >> 6;
    const int lane = threadIdx.x & 63;
    const int row  = blockIdx.x * 4 + wave;
    const float* xr = x + (size_t)row * 512;
    const int c0 = lane * 8;

    float4 v0 = *(const float4*)(xr + c0);
    float4 v1 = *(const float4*)(xr + c0 + 4);
    float s  = v0.x + v0.y + v0.z + v0.w + v1.x + v1.y + v1.z + v1.w;
    float ss = v0.x*v0.x + v0.y*v0.y + v0.z*v0.z + v0.w*v0.w
             + v1.x*v1.x + v1.y*v1.y + v1.z*v1.z + v1.w*v1.w;
#pragma unroll
    for (int m = 32; m > 0; m >>= 1) { s += __shfl_xor(s, m); ss += __shfl_xor(ss, m); }
    const float mean = s * (1.0f / 512.0f);
    const float var  = ss * (1.0f / 512.0f) - mean * mean;
    const float rs   = rsqrtf(var + 1e-5f);

    float4 g0 = *(const float4*)(g + c0);
    float4 g1 = *(const float4*)(g + c0 + 4);
    float4 b0 = *(const float4*)(b + c0);
    float4 b1 = *(const float4*)(b + c0 + 4);

    short8 o;
    o[0] = (short)f2bf((v0.x - mean) * rs * g0.x + b0.x);
    o[1] = (short)f2bf((v0.y - mean) * rs * g0.y + b0.y);
    o[2] = (short)f2bf((v0.z - mean) * rs * g0.z + b0.z);
    o[3] = (short)f2bf((v0.w - mean) * rs * g0.w + b0.w);
    o[4] = (short)f2bf((v1.x - mean) * rs * g1.x + b1.x);
    o[5] = (short)f2bf((v1.y - mean) * rs * g1.y + b1.y);
    o[6] = (short)f2bf((v1.z - mean) * rs * g1.z + b1.z);
    o[7] = (short)f2bf((v1.w - mean) * rs * g1.w + b1.w);
    *(short8*)(y + (size_t)row * 512 + c0) = o;
}

// ---------------- fused step GEMM ----------------
// Block: 512 thr = 8 waves. Tile: 64 rows (blockIdx.y) x 512 cols (wave*64 each).
// A[2048][K=1024] = [xn (bf16, [2048][512]) | hbuf[:, hoff..hoff+511] (bf16)]
// B = W[N][1024] bf16 row-major-K, N row = blockIdx.x*512 + wave*64 + nf*16 + llo.
// EPI 0 (rz): nb==0 -> r=sigmoid(+br), write bf16(r*hn_f32) to hbuf[:,512:]; nb==1 -> z=sigmoid(+bz) -> z_f32
// EPI 1 (c):  h_new=(1-z)*hn+z*tanh(+bc); cell-LN -> states[t]; then LN(h)*exp(-dt) -> hn_f32 + hbuf[:,0:512]
template<int EPI>
__global__ __launch_bounds__(512)
void gemm_cell(const unsigned short* __restrict__ xn,
               unsigned short* __restrict__ hbuf,
               const unsigned short* __restrict__ W,
               const float* __restrict__ bias_r, const float* __restrict__ bias_z,
               float* __restrict__ hn_f32, float* __restrict__ z_f32,
               const float* __restrict__ gc, const float* __restrict__ bcl,
               const float* __restrict__ gh, const float* __restrict__ bh,
               const float* __restrict__ ts, float* __restrict__ states, int t)
{
    const int tid  = threadIdx.x;
    const int wave = tid >> 6;
    const int lane = tid & 63;
    const int lhi  = lane >> 4;
    const int llo  = lane & 15;
    const int m0   = blockIdx.y * 64;
    const int nb   = blockIdx.x;
    const int hoff = (EPI == 0) ? 0 : 512;

    f32x4 acc[4][4] = {};

    // K = 0..511 : xn part
    for (int k0 = 0; k0 < 512; k0 += 32) {
        const int kk = k0 + lhi * 8;
        short8 a[4], b[4];
#pragma unroll
        for (int mf = 0; mf < 4; ++mf)
            a[mf] = *(const short8*)(xn + (size_t)(m0 + mf * 16 + llo) * 512 + kk);
#pragma unroll
        for (int nf = 0; nf < 4; ++nf)
            b[nf] = *(const short8*)(W + (size_t)(nb * 512 + wave * 64 + nf * 16 + llo) * 1024 + kk);
#pragma unroll
        for (int mf = 0; mf < 4; ++mf)
#pragma unroll
            for (int nf = 0; nf < 4; ++nf)
                acc[mf][nf] = __builtin_amdgcn_mfma_f32_16x16x32_bf16(a[mf], b[nf], acc[mf][nf], 0, 0, 0);
    }
    // K = 512..1023 : h part (hn or r*hn)
    for (int k0 = 512; k0 < 1024; k0 += 32) {
        const int kk = k0 + lhi * 8;
        short8 a[4], b[4];
#pragma unroll
        for (int mf = 0; mf < 4; ++mf)
            a[mf] = *(const short8*)(hbuf + (size_t)(m0 + mf * 16 + llo) * 1024 + hoff + (kk - 512));
#pragma unroll
        for (int nf = 0; nf < 4; ++nf)
            b[nf] = *(const short8*)(W + (size_t)(nb * 512 + wave * 64 + nf * 16 + llo) * 1024 + kk);
#pragma unroll
        for (int mf = 0; mf < 4; ++mf)
#pragma unroll
            for (int nf = 0; nf < 4; ++nf)
                acc[mf][nf] = __builtin_amdgcn_mfma_f32_16x16x32_bf16(a[mf], b[nf], acc[mf][nf], 0, 0, 0);
    }

    if (EPI == 0) {
        const float* bias = (nb == 0) ? bias_r : bias_z;
#pragma unroll
        for (int mf = 0; mf < 4; ++mf)
#pragma unroll
            for (int i = 0; i < 4; ++i) {
                const int row = m0 + mf * 16 + lhi * 4 + i;
#pragma unroll
                for (int nf = 0; nf < 4; ++nf) {
                    const int col = wave * 64 + nf * 16 + llo;
                    const float sg = sigmoidf_(acc[mf][nf][i] + bias[col]);
                    if (nb == 0) {
                        hbuf[(size_t)row * 1024 + 512 + col] = f2bf(sg * hn_f32[(size_t)row * 512 + col]);
                    } else {
                        z_f32[(size_t)row * 512 + col] = sg;
                    }
                }
            }
        return;
    }

    // ---- EPI == 1 ----
    __shared__ float red_s[64][8];
    __shared__ float red_q[64][8];

#pragma unroll
    for (int mf = 0; mf < 4; ++mf)
#pragma unroll
        for (int i = 0; i < 4; ++i) {
            const int row = m0 + mf * 16 + lhi * 4 + i;
#pragma unroll
            for (int nf = 0; nf < 4; ++nf) {
                const int col = wave * 64 + nf * 16 + llo;
                const size_t off = (size_t)row * 512 + col;
                const float v  = acc[mf][nf][i] + bias_r[col];
                const float z  = z_f32[off];
                const float hv = hn_f32[off];
                acc[mf][nf][i] = (1.0f - z) * hv + z * tanhf_(v);
            }
        }

    float mu[4][4], rstd[4][4];
    // pass 1: stats of h_new
#pragma unroll
    for (int mf = 0; mf < 4; ++mf)
#pragma unroll
        for (int i = 0; i < 4; ++i) {
            float s = 0.f, q = 0.f;
#pragma unroll
            for (int nf = 0; nf < 4; ++nf) { const float v = acc[mf][nf][i]; s += v; q += v * v; }
#pragma unroll
            for (int m = 8; m >= 1; m >>= 1) { s += __shfl_xor(s, m); q += __shfl_xor(q, m); }
            if (llo == 0) { red_s[mf * 16 + lhi * 4 + i][wave] = s; red_q[mf * 16 + lhi * 4 + i][wave] = q; }
        }
    __syncthreads();
#pragma unroll
    for (int mf = 0; mf < 4; ++mf)
#pragma unroll
        for (int i = 0; i < 4; ++i) {
            const int rl = mf * 16 + lhi * 4 + i;
            float s = 0.f, q = 0.f;
#pragma unroll
            for (int w2 = 0; w2 < 8; ++w2) { s += red_s[rl][w2]; q += red_q[rl][w2]; }
            const float m_ = s * (1.0f / 512.0f);
            const float var = q * (1.0f / 512.0f) - m_ * m_;
            mu[mf][i] = m_;
            rstd[mf][i] = rsqrtf(var + 1e-5f);
        }
    // states write + keep normalized h in acc
#pragma unroll
    for (int mf = 0; mf < 4; ++mf)
#pragma unroll
        for (int i = 0; i < 4; ++i) {
            const int row = m0 + mf * 16 + lhi * 4 + i;
#pragma unroll
            for (int nf = 0; nf < 4; ++nf) {
                const int col = wave * 64 + nf * 16 + llo;
                const float h = (acc[mf][nf][i] - mu[mf][i]) * rstd[mf][i] * gc[col] + bcl[col];
                states[(size_t)row * 512 + col] = h;
                acc[mf][nf][i] = h;
            }
        }
    if (t < TT - 1) {
        __syncthreads();
        // pass 2: stats of h
#pragma unroll
        for (int mf = 0; mf < 4; ++mf)
#pragma unroll
            for (int i = 0; i < 4; ++i) {
                float s = 0.f, q = 0.f;
#pragma unroll
                for (int nf = 0; nf < 4; ++nf) { const float v = acc[mf][nf][i]; s += v; q += v * v; }
#pragma unroll
                for (int m = 8; m >= 1; m >>= 1) { s += __shfl_xor(s, m); q += __shfl_xor(q, m); }
                if (llo == 0) { red_s[mf * 16 + lhi * 4 + i][wave] = s; red_q[mf * 16 + lhi * 4 + i][wave] = q; }
            }
        __syncthreads();
#pragma unroll
        for (int mf = 0; mf < 4; ++mf)
#pragma unroll
            for (int i = 0; i < 4; ++i) {
                const int rl = mf * 16 + lhi * 4 + i;
                float s = 0.f, q = 0.f;
#pragma unroll
                for (int w2 = 0; w2 < 8; ++w2) { s += red_s[rl][w2]; q += red_q[rl][w2]; }
                const float m_ = s * (1.0f / 512.0f);
                const float var = q * (1.0f / 512.0f) - m_ * m_;
                mu[mf][i] = m_;
                rstd[mf][i] = rsqrtf(var + 1e-5f);
            }
#pragma unroll
        for (int mf = 0; mf < 4; ++mf)
#pragma unroll
            for (int i = 0; i < 4; ++i) {
                const int row = m0 + mf * 16 + lhi * 4 + i;
                float dt = ts[(size_t)row * TT + t + 1] - ts[(size_t)row * TT + t];
                dt = fminf(fmaxf(dt, 0.0f), 10.0f);
                const float dec = expf(-dt);
#pragma unroll
                for (int nf = 0; nf < 4; ++nf) {
                    const int col = wave * 64 + nf * 16 + llo;
                    const float hn = ((acc[mf][nf][i] - mu[mf][i]) * rstd[mf][i] * gh[col] + bh[col]) * dec;
                    hn_f32[(size_t)row * 512 + col] = hn;
                    hbuf[(size_t)row * 1024 + col] = f2bf(hn);
                }
            }
    }
}

// ---------------- final projection + residual + LN (in-place safe) ----------------
__global__ __launch_bounds__(512)
void proj_kernel(const float* __restrict__ S, const unsigned short* __restrict__ Wo,
                 const float* __restrict__ bo, const float* __restrict__ seq,
                 const float* __restrict__ gf, const float* __restrict__ bf,
                 float* __restrict__ out)
{
    const int tid  = threadIdx.x;
    const int wave = tid >> 6;
    const int lane = tid & 63;
    const int lhi  = lane >> 4;
    const int llo  = lane & 15;
    const long m0  = (long)blockIdx.x * 64;

    f32x4 acc[4][4] = {};
    for (int k0 = 0; k0 < 512; k0 += 32) {
        const int kk = k0 + lhi * 8;
        short8 a[4], b[4];
#pragma unroll
        for (int mf = 0; mf < 4; ++mf) {
            const float* ap = S + (size_t)(m0 + mf * 16 + llo) * 512 + kk;
            float4 f0 = *(const float4*)ap;
            float4 f1 = *(const float4*)(ap + 4);
            short8 av;
            av[0] = (short)f2bf(f0.x); av[1] = (short)f2bf(f0.y);
            av[2] = (short)f2bf(f0.z); av[3] = (short)f2bf(f0.w);
            av[4] = (short)f2bf(f1.x); av[5] = (short)f2bf(f1.y);
            av[6] = (short)f2bf(f1.z); av[7] = (short)f2bf(f1.w);
            a[mf] = av;
        }
#pragma unroll
        for (int nf = 0; nf < 4; ++nf)
            b[nf] = *(const short8*)(Wo + (size_t)(wave * 64 + nf * 16 + llo) * 512 + kk);
#pragma unroll
        for (int mf = 0; mf < 4; ++mf)
#pragma unroll
            for (int nf = 0; nf < 4; ++nf)
                acc[mf][nf] = __builtin_amdgcn_mfma_f32_16x16x32_bf16(a[mf], b[nf], acc[mf][nf], 0, 0, 0);
    }

    __shared__ float red_s[64][8];
    __shared__ float red_q[64][8];

    // val = acc + bo + seq
#pragma unroll
    for (int mf = 0; mf < 4; ++mf)
#pragma unroll
        for (int i = 0; i < 4; ++i) {
            const long row = m0 + mf * 16 + lhi * 4 + i;
#pragma unroll
            for (int nf = 0; nf < 4; ++nf) {
                const int col = wave * 64 + nf * 16 + llo;
                acc[mf][nf][i] += bo[col] + seq[(size_t)row * 512 + col];
            }
        }
    float mu[4][4], rstd[4][4];
#pragma unroll
    for (int mf = 0; mf < 4; ++mf)
#pragma unroll
        for (int i = 0; i < 4; ++i) {
            float s = 0.f, q = 0.f;
#pragma unroll
            for (int nf = 0; nf < 4; ++nf) { const float v = acc[mf][nf][i]; s += v; q += v * v; }
#pragma unroll
            for (int m = 8; m >= 1; m >>= 1) { s += __shfl_xor(s, m); q += __shfl_xor(q, m); }
            if (llo == 0) { red_s[mf * 16 + lhi * 4 + i][wave] = s; red_q[mf * 16 + lhi * 4 + i][wave] = q; }
        }
    __syncthreads();
#pragma unroll
    for (int mf = 0; mf < 4; ++mf)
#pragma unroll
        for (int i = 0; i < 4; ++i) {
            const int rl = mf * 16 + lhi * 4 + i;
            float s = 0.f, q = 0.f;
#pragma unroll
            for (int w2 = 0; w2 < 8; ++w2) { s += red_s[rl][w2]; q += red_q[rl][w2]; }
            const float m_ = s * (1.0f / 512.0f);
            const float var = q * (1.0f / 512.0f) - m_ * m_;
            mu[mf][i] = m_;
            rstd[mf][i] = rsqrtf(var + 1e-5f);
        }
#pragma unroll
    for (int mf = 0; mf < 4; ++mf)
#pragma unroll
        for (int i = 0; i < 4; ++i) {
            const long row = m0 + mf * 16 + lhi * 4 + i;
#pragma unroll
            for (int nf = 0; nf < 4; ++nf) {
                const int col = wave * 64 + nf * 16 + llo;
                out[(size_t)row * 512 + col] = (acc[mf][nf][i] - mu[mf][i]) * rstd[mf][i] * gf[col] + bf[col];
            }
        }
}

extern "C" void kernel_launch(void* const* d_in, const int* in_sizes, int n_in,
                              void* d_out, int out_size, void* d_ws, size_t ws_size,
                              hipStream_t stream) {
    const float* seq = (const float*)d_in[0];
    const float* ts  = (const float*)d_in[1];
    const float* Wr  = (const float*)d_in[2];
    const float* br  = (const float*)d_in[3];
    const float* Wz  = (const float*)d_in[4];
    const float* bz  = (const float*)d_in[5];
    const float* Wc  = (const float*)d_in[6];
    const float* bc  = (const float*)d_in[7];
    const float* Wo  = (const float*)d_in[8];
    const float* bo  = (const float*)d_in[9];
    const float* gx  = (const float*)d_in[10];
    const float* bx  = (const float*)d_in[11];
    const float* gh  = (const float*)d_in[12];
    const float* bh  = (const float*)d_in[13];
    const float* gc  = (const float*)d_in[14];
    const float* bcl = (const float*)d_in[15];
    const float* gf  = (const float*)d_in[16];
    const float* bf  = (const float*)d_in[17];
    float* out = (float*)d_out;

    char* w = (char*)d_ws;
    float* hn_f32 = (float*)w;            w += (size_t)BB * 512 * 4;
    float* z_f32  = (float*)w;            w += (size_t)BB * 512 * 4;
    unsigned short* Wcat = (unsigned short*)w; w += (size_t)1024 * 1024 * 2;
    unsigned short* Wc_b = (unsigned short*)w; w += (size_t)512 * 1024 * 2;
    unsigned short* Wo_b = (unsigned short*)w; w += (size_t)512 * 512 * 2;
    unsigned short* hbuf = (unsigned short*)w; w += (size_t)BB * 1024 * 2;
    unsigned short* xn_all = (unsigned short*)w;
    const size_t fixed = (size_t)(w - (char*)d_ws);
    const size_t xn_bytes = (size_t)TT * BB * 512 * 2;
    const bool big = ws_size >= fixed + xn_bytes;

    hipMemsetAsync(hn_f32, 0, (size_t)BB * 512 * 4, stream);
    hipMemsetAsync(hbuf, 0, (size_t)BB * 1024 * 2, stream);

    cvt_kernel<<<(512 * 1024 + 255) / 256, 256, 0, stream>>>(Wr, Wcat, 512 * 1024);
    cvt_kernel<<<(512 * 1024 + 255) / 256, 256, 0, stream>>>(Wz, Wcat + (size_t)512 * 1024, 512 * 1024);
    cvt_kernel<<<(512 * 1024 + 255) / 256, 256, 0, stream>>>(Wc, Wc_b, 512 * 1024);
    cvt_kernel<<<(512 * 512 + 255) / 256, 256, 0, stream>>>(Wo, Wo_b, 512 * 512);

    if (big)
        ln_x_kernel<<<(TT * BB) / 4, 256, 0, stream>>>(seq, gx, bx, xn_all);

    for (int t = 0; t < TT; ++t) {
        const unsigned short* xn_t;
        if (big) {
            xn_t = xn_all + (size_t)t * BB * 512;
        } else {
            ln_x_kernel<<<BB / 4, 256, 0, stream>>>(seq + (size_t)t * BB * 512, gx, bx, xn_all);
            xn_t = xn_all;
        }
        gemm_cell<0><<<dim3(2, 32), 512, 0, stream>>>(xn_t, hbuf, Wcat, br, bz, hn_f32, z_f32,
                                                      nullptr, nullptr, nullptr, nullptr, nullptr, nullptr, t);
        gemm_cell<1><<<dim3(1, 32), 512, 0, stream>>>(xn_t, hbuf, Wc_b, bc, nullptr, hn_f32, z_f32,
                                                      gc, bcl, gh, bh, ts, out + (size_t)t * BB * 512, t);
    }
    proj_kernel<<<2048, 512, 0, stream>>>(out, Wo_b, bo, seq, gf, bf, out);
}